// Round 1
// baseline (63.992 us; speedup 1.0000x reference)
//
#include <hip/hip_runtime.h>

#define NQ 24
#define BATCH 4096

// One tiny kernel: compute log_psi analytically, broadcast to all BATCH outputs.
//
// Derivation (replaces the 2^24 statevector entirely):
//   |psi_i> = RY(t1) RX(t0) |0>  =>  <Z>_i = cos(t0) * cos(t1)            (product state)
//   CNOT chain (ctrl i -> tgt i+1, i ascending) maps bit_i -> XOR of bits 0..i,
//   bits are independent  =>  <Z_i>_final = prod_{j<=i} cos(t0_j) cos(t1_j)
//   log_psi = sum_i coeffs[i] * prefix_prod_i
__global__ __launch_bounds__(256) void quantum_analytic_kernel(
    const float* __restrict__ params,   // (NQ*2,)  [t0_0, t1_0, t0_1, t1_1, ...] via reshape(n,2)
    const float* __restrict__ coeffs,   // (NQ,)
    float* __restrict__ out)            // (BATCH,)
{
    __shared__ float s_val;
    if (threadIdx.x == 0) {
        float prod = 1.0f;
        float acc  = 0.0f;
#pragma unroll
        for (int i = 0; i < NQ; ++i) {
            // mirror reference numerics: cos(p) computed as c^2 - s^2 of half-angle
            float h0 = 0.5f * params[2 * i + 0];
            float h1 = 0.5f * params[2 * i + 1];
            float c0 = cosf(h0), s0 = sinf(h0);
            float c1 = cosf(h1), s1 = sinf(h1);
            float z = (c0 * c0 - s0 * s0) * (c1 * c1 - s1 * s1);
            prod *= z;
            acc = fmaf(coeffs[i], prod, acc);
        }
        s_val = acc;
    }
    __syncthreads();
    float4 v = make_float4(s_val, s_val, s_val, s_val);
    // grid = BATCH / (256 threads * 4 floats) = 4 blocks; one float4 per thread
    int idx = blockIdx.x * blockDim.x + threadIdx.x;   // float4 index
    reinterpret_cast<float4*>(out)[idx] = v;
}

extern "C" void kernel_launch(void* const* d_in, const int* in_sizes, int n_in,
                              void* d_out, int out_size, void* d_ws, size_t ws_size,
                              hipStream_t stream) {
    // inputs: d_in[0]=x (unused), d_in[1]=quantum_params (NQ*2), d_in[2]=coeffs (NQ)
    const float* params = (const float*)d_in[1];
    const float* coeffs = (const float*)d_in[2];
    float* out = (float*)d_out;

    constexpr int THREADS = 256;
    constexpr int F4 = BATCH / 4;              // 1024 float4 stores
    constexpr int BLOCKS = F4 / THREADS;       // 4 blocks
    quantum_analytic_kernel<<<BLOCKS, THREADS, 0, stream>>>(params, coeffs, out);
}